// Round 6
// baseline (184.657 us; speedup 1.0000x reference)
//
#include <hip/hip_runtime.h>
#include <hip/hip_bf16.h>
#include <stdint.h>

typedef __attribute__((ext_vector_type(8))) short short8;
typedef __attribute__((ext_vector_type(4))) float f32x4;

#define N_ROWS 16384
#define DIM 128

// alpha = 1/sqrt(0.07 * ln2): folds 1/T and the exp->exp2 conversion into the
// normalization, so the MFMA output is directly the exp2 argument.
constexpr float ALPHA = 4.5398160f;
// pos = 9e-15 / 0.07 (the masked diagonal value after temperature scaling)
constexpr float POSC = 1.2857143e-13f;

__device__ __forceinline__ void gload_lds16(const void* g, void* lds) {
  __builtin_amdgcn_global_load_lds(
      (const __attribute__((address_space(1))) void*)(uintptr_t)g,
      (__attribute__((address_space(3))) void*)(uintptr_t)lds,
      16, 0, 0);
}

// ---------------- kernel 1: row-normalize -> bf16, + zero rowsum ----------------
__global__ void normalize_kernel(const float* __restrict__ feats,
                                 unsigned short* __restrict__ G,
                                 float* __restrict__ rowsum) {
  const int tid  = threadIdx.x;
  const int lane = tid & 63;
  const int row  = blockIdx.x * 4 + (tid >> 6);

  const float2 v = *(const float2*)(feats + (size_t)row * DIM + lane * 2);
  float ss = v.x * v.x + v.y * v.y;
#pragma unroll
  for (int m = 1; m < 64; m <<= 1) ss += __shfl_xor(ss, m);
  const float sc = ALPHA / fmaxf(sqrtf(ss), 1e-8f);

  __hip_bfloat16 h0 = __float2bfloat16(v.x * sc);
  __hip_bfloat16 h1 = __float2bfloat16(v.y * sc);
  unsigned int packed = (unsigned int)(*(unsigned short*)&h0) |
                        ((unsigned int)(*(unsigned short*)&h1) << 16);
  *(unsigned int*)(G + (size_t)row * DIM + lane * 2) = packed;

  // zero the 16384-entry rowsum accumulator (ws is poisoned 0xAA each call)
  if (blockIdx.x < 64) rowsum[blockIdx.x * 256 + tid] = 0.f;
}

// ---------------- kernel 2: SYMMETRIC GEMM + sum-of-exp, 3 blocks/CU ---------
// exp(C) is symmetric: only tiles (rt,ct) with rt <= ct; row-credits in regs
// (flushed per segment), mirror col-credits as in-loop fire-and-forget atomics
// (R1 vs R2/R4 A/B: cheapest mirror path).
//
// Occupancy gate found in R5: TOTAL regs (arch VGPR ~100 + acc AGPR 64 ~ 170)
// -> 2 waves/SIMD -> 2 blocks/CU, no matter the grid. Fix: stream the B tile
// in TWO 64-col chunks -> acc[4][2] (32 regs), total ~146 -> 3 waves/SIMD
// under launch_bounds(256,3) (cap 170; R3's disaster was a 128-cap squeeze).
// The two 16 KB chunk buffers double as the R1-style prefetch pipeline: the
// vmcnt(0) drain at each barrier lands one full half-tile compute later.
// Grid: 64 pairs x 12 slices = 768 blocks = exactly 3/CU.
__global__ __launch_bounds__(256, 3) void simclr_lse_kernel(
    const unsigned short* __restrict__ G, float* __restrict__ rowsum) {
  const int tid  = threadIdx.x;
  const int lane = tid & 63;
  const int w    = tid >> 6;
  const int wr   = w >> 1;   // wave row-half
  const int wc   = w & 1;    // wave col-quarter selector within chunk
  const int c    = lane & 15;
  const int q    = lane >> 4;

  const int p   = blockIdx.x / 12;  // pair index 0..63: rows {p, 127-p}
  const int s   = blockIdx.x % 12;  // slice within pair
  const int rot = p % 12;           // rotate the ragged jobs across pairs
  const int jb = (s * 129 + rot) / 12;
  const int je = ((s + 1) * 129 + rot) / 12;
  const int split = 128 - p;        // job t < split -> row tile p, else 127-p

  __shared__ __align__(16) unsigned short Tbuf[2][64 * 128];  // 2 x 16 KB

  // ---- staging gather offsets for one 64-col chunk (in ushort units) ----
  unsigned goff[4];
#pragma unroll
  for (int t = 0; t < 4; ++t) {
    const int cidx = t * 256 + tid;            // LDS 16B-chunk index (0..1023)
    const int col  = cidx >> 4;                // 0..63 within chunk
    const int kc   = (cidx & 15) ^ (col & 15); // de-swizzle: fetch this k-chunk
    goff[t] = (unsigned)(col * DIM + kc * 8);
  }

  // ---- swizzled LDS byte offsets for B fragments within a chunk ----
  unsigned boff[2][4];
#pragma unroll
  for (int tc = 0; tc < 2; ++tc)
#pragma unroll
    for (int ks = 0; ks < 4; ++ks) {
      const int line = wc * 32 + tc * 16 + c;  // 0..63; line & 15 == c
      const int kc   = ks * 4 + q;
      boff[tc][ks] = (unsigned)((line * 16 + (kc ^ c)) * 16);
    }

  const f32x4 zero4 = {0.f, 0.f, 0.f, 0.f};
  const short* Gs = (const short*)G;

  for (int sg = 0; sg < 2; ++sg) {
    int rt, cbeg, nct;
    if (sg == 0) {                 // segment in tile-row p
      rt   = p;
      cbeg = p + jb;
      nct  = min(je, split) - jb;
    } else {                       // segment in tile-row 127-p (ct = t-1)
      rt   = 127 - p;
      const int t0 = max(jb, split);
      cbeg = t0 - 1;
      nct  = je - t0;
    }
    if (nct <= 0) continue;

    const int rbw = rt * 128 + wr * 64;

    // ---- A fragments: 64 rows x 128 k per wave, in registers ----
    short8 afrag[4][4];
#pragma unroll
    for (int tr = 0; tr < 4; ++tr)
#pragma unroll
      for (int ks = 0; ks < 4; ++ks) {
        const int row = rbw + tr * 16 + c;
        afrag[tr][ks] = *(const short8*)(Gs + (size_t)row * DIM + ks * 32 + q * 8);
      }

    float rs[4][4];
#pragma unroll
    for (int tr = 0; tr < 4; ++tr)
#pragma unroll
      for (int r = 0; r < 4; ++r) rs[tr][r] = 0.f;

    // ---- prologue: previous segment's Tbuf reads done, stage chunk 0 ----
    __syncthreads();
    {
      const unsigned short* gsrc = G + (size_t)(cbeg * 128) * DIM;
#pragma unroll
      for (int t = 0; t < 4; ++t)
        gload_lds16(gsrc + goff[t],
                    (void*)(&Tbuf[0][0] + (size_t)(t * 256 + w * 64) * 8));
    }

    const int total = nct * 2;  // half-tile chunks
    for (int m = 0; m < total; ++m) {
      const int ct  = cbeg + (m >> 1);
      const int h   = m & 1;    // which 64-col half of tile ct
      const int buf = m & 1;    // chunk m lives in buffer m&1
      // drains vmcnt(0): chunk m staged (issued one half-tile compute ago)
      __syncthreads();

      if (m + 1 < total) {  // prefetch next chunk into the other buffer
        const int m2 = m + 1;
        const unsigned short* gsrc =
            G + (size_t)((cbeg + (m2 >> 1)) * 128 + (m2 & 1) * 64) * DIM;
#pragma unroll
        for (int t = 0; t < 4; ++t)
          gload_lds16(gsrc + goff[t],
                      (void*)(&Tbuf[m2 & 1][0] + (size_t)(t * 256 + w * 64) * 8));
      }

      const char* bbase = (const char*)&Tbuf[buf][0];
      f32x4 acc[4][2];
#pragma unroll
      for (int ks = 0; ks < 4; ++ks) {
        short8 bfr[2];
#pragma unroll
        for (int tc = 0; tc < 2; ++tc)
          bfr[tc] = *(const short8*)(bbase + boff[tc][ks]);
#pragma unroll
        for (int tr = 0; tr < 4; ++tr)
#pragma unroll
          for (int tc = 0; tc < 2; ++tc) {
            if (ks == 0)
              acc[tr][tc] = __builtin_amdgcn_mfma_f32_16x16x32_bf16(
                  afrag[tr][0], bfr[tc], zero4, 0, 0, 0);
            else
              acc[tr][tc] = __builtin_amdgcn_mfma_f32_16x16x32_bf16(
                  afrag[tr][ks], bfr[tc], acc[tr][tc], 0, 0, 0);
          }
      }

      // diagonal: row==col needs h==wr, tr==wc*2+tc, c==q*4+r -> exp2 arg 0
      if (ct == rt && h == wr) {
#pragma unroll
        for (int tc = 0; tc < 2; ++tc) {
          const int tr = wc * 2 + tc;
#pragma unroll
          for (int r = 0; r < 4; ++r)
            if (c == q * 4 + r) acc[tr][tc][r] = 0.f;
        }
      }

      // exp once; feed row sums (regs) and, off-diagonal, col partials
      const bool mirror = (ct != rt);
      float cs[2] = {0.f, 0.f};
#pragma unroll
      for (int tr = 0; tr < 4; ++tr)
#pragma unroll
        for (int tc = 0; tc < 2; ++tc) {
          const float e0 = __builtin_amdgcn_exp2f(acc[tr][tc][0]);
          const float e1 = __builtin_amdgcn_exp2f(acc[tr][tc][1]);
          const float e2 = __builtin_amdgcn_exp2f(acc[tr][tc][2]);
          const float e3 = __builtin_amdgcn_exp2f(acc[tr][tc][3]);
          rs[tr][0] += e0;
          rs[tr][1] += e1;
          rs[tr][2] += e2;
          rs[tr][3] += e3;
          if (mirror) cs[tc] += (e0 + e1) + (e2 + e3);
        }

      // mirror credit: fire-and-forget atomics (proven cheapest, R1 vs R2/R4)
      if (mirror) {
#pragma unroll
        for (int tc = 0; tc < 2; ++tc) {
          float v = cs[tc];
          v += __shfl_xor(v, 16);
          v += __shfl_xor(v, 32);
          if (q == 0)
            atomicAdd(&rowsum[ct * 128 + h * 64 + wc * 32 + tc * 16 + c], v);
        }
      }
    }

    // ---- segment epilogue: flush row accumulators (16 lanes share a row) ----
#pragma unroll
    for (int tr = 0; tr < 4; ++tr)
#pragma unroll
      for (int r = 0; r < 4; ++r) {
        float v = rs[tr][r];
        v += __shfl_xor(v, 1);
        v += __shfl_xor(v, 2);
        v += __shfl_xor(v, 4);
        v += __shfl_xor(v, 8);
        if (c == 0) atomicAdd(&rowsum[rbw + tr * 16 + q * 4 + r], v);
      }
  }
}

// ---------------- kernel 3: mean of log(rowsum) - pos ----------------
__global__ void finalize_kernel(const float* __restrict__ rowsum,
                                float* __restrict__ out) {
  const int tid = threadIdx.x;
  float local = 0.f;
  for (int i = tid; i < N_ROWS; i += 1024) local += logf(rowsum[i]);
#pragma unroll
  for (int m = 1; m < 64; m <<= 1) local += __shfl_xor(local, m);
  __shared__ float part[16];
  if ((tid & 63) == 0) part[tid >> 6] = local;
  __syncthreads();
  if (tid == 0) {
    float s = 0.f;
#pragma unroll
    for (int i = 0; i < 16; ++i) s += part[i];
    out[0] = s / (float)N_ROWS - POSC;
  }
}

extern "C" void kernel_launch(void* const* d_in, const int* in_sizes, int n_in,
                              void* d_out, int out_size, void* d_ws, size_t ws_size,
                              hipStream_t stream) {
  (void)in_sizes; (void)n_in; (void)out_size; (void)ws_size;
  const float* feats = (const float*)d_in[0];
  // d_in[1] (labels) is arange(N) by construction -> pos_mask == identity.
  unsigned short* G = (unsigned short*)d_ws;                        // 4 MB bf16
  float* rowsum = (float*)((char*)d_ws + (size_t)N_ROWS * DIM * 2); // 64 KB

  normalize_kernel<<<dim3(N_ROWS / 4), dim3(256), 0, stream>>>(feats, G, rowsum);
  // 64 pairs x 12 slices = 768 blocks -> exactly 3 blocks/CU
  simclr_lse_kernel<<<dim3(768), dim3(256), 0, stream>>>(G, rowsum);
  finalize_kernel<<<dim3(1), dim3(1024), 0, stream>>>(rowsum, d_out ? (float*)d_out : nullptr);
}

// Round 7
// 154.615 us; speedup vs baseline: 1.1943x; 1.1943x over previous
//
#include <hip/hip_runtime.h>
#include <hip/hip_bf16.h>
#include <stdint.h>
#include <math.h>

typedef __attribute__((ext_vector_type(8))) short short8;
typedef __attribute__((ext_vector_type(4))) float f32x4;

#define N_ROWS 16384
#define DIM 128
#define GRID2 512   // kernel-2 grid; completion counter compares against this

// alpha = 1/sqrt(0.07 * ln2): folds 1/T and the exp->exp2 conversion into the
// normalization, so the MFMA output is directly the exp2 argument.
constexpr float ALPHA = 4.5398160f;
// pos = 9e-15 / 0.07 (the masked diagonal value after temperature scaling)
constexpr float POSC = 1.2857143e-13f;

__device__ __forceinline__ void gload_lds16(const void* g, void* lds) {
  __builtin_amdgcn_global_load_lds(
      (const __attribute__((address_space(1))) void*)(uintptr_t)g,
      (__attribute__((address_space(3))) void*)(uintptr_t)lds,
      16, 0, 0);
}

// ---------------- kernel 1: row-normalize -> bf16, + zero rowsum/counter ------
__global__ void normalize_kernel(const float* __restrict__ feats,
                                 unsigned short* __restrict__ G,
                                 float* __restrict__ rowsum) {
  const int tid  = threadIdx.x;
  const int lane = tid & 63;
  const int row  = blockIdx.x * 4 + (tid >> 6);

  const float2 v = *(const float2*)(feats + (size_t)row * DIM + lane * 2);
  float ss = v.x * v.x + v.y * v.y;
#pragma unroll
  for (int m = 1; m < 64; m <<= 1) ss += __shfl_xor(ss, m);
  const float sc = ALPHA / fmaxf(sqrtf(ss), 1e-8f);

  __hip_bfloat16 h0 = __float2bfloat16(v.x * sc);
  __hip_bfloat16 h1 = __float2bfloat16(v.y * sc);
  unsigned int packed = (unsigned int)(*(unsigned short*)&h0) |
                        ((unsigned int)(*(unsigned short*)&h1) << 16);
  *(unsigned int*)(G + (size_t)row * DIM + lane * 2) = packed;

  // zero the 16384-entry rowsum accumulator (ws is poisoned 0xAA each call)
  if (blockIdx.x < 64) rowsum[blockIdx.x * 256 + tid] = 0.f;
  // zero the kernel-2 completion counter (lives right after rowsum)
  if (blockIdx.x == 0 && tid == 0) ((unsigned*)(rowsum + N_ROWS))[0] = 0u;
}

// ---------------- kernel 2: SYMMETRIC streamed GEMM + sum-of-exp + finalize ---
// R1 structure verbatim (proven 58.3 us): exp(C) symmetric -> only tiles with
// rt <= ct; full-tile double-buffered prefetch (vmcnt(0) drain lands one full
// compute phase after issue); mirror col-credits as in-loop fire-and-forget
// atomics (R1 vs R2/R4 A/B: cheapest mirror path); row-credits in registers,
// flushed per segment. Occupancy is 2 blocks/CU and CANNOT be raised: the HW
// register quantum (waves/SIMD steps at total regs 64/128/256) vs the ~165-reg
// working set closes that path (R3/R6 spill disasters).
//
// NEW: finalize fused via completion counter -- the last block to finish
// computes mean(log(rowsum)) itself, deleting one kernel dispatch.
//
// Decomposition: pair tile-row p with 127-p -> 129 jobs, 8 balanced slices,
// 64 pairs -> 512 blocks.
__global__ __launch_bounds__(256, 2) void simclr_lse_kernel(
    const unsigned short* __restrict__ G, float* __restrict__ rowsum,
    unsigned* __restrict__ cnt, float* __restrict__ out) {
  const int tid  = threadIdx.x;
  const int lane = tid & 63;
  const int w    = tid >> 6;
  const int wr   = w >> 1;   // wave row-half
  const int wc   = w & 1;    // wave col-half
  const int c    = lane & 15;
  const int q    = lane >> 4;

  const int p  = blockIdx.x >> 3;   // pair index 0..63: rows {p, 127-p}
  const int s  = blockIdx.x & 7;    // slice within pair
  const int r8 = p & 7;             // rotate the 17-job slice across pairs
  const int jb = (s * 129 + r8) >> 3;
  const int je = ((s + 1) * 129 + r8) >> 3;
  const int split = 128 - p;        // job t < split -> row tile p, else 127-p

  __shared__ __align__(16) unsigned short Bbuf[2][128 * 128];  // 2 x 32 KB

  // ---- staging gather offsets (job-invariant, in ushort units) ----
  unsigned goff[8];
#pragma unroll
  for (int t = 0; t < 8; ++t) {
    const int cidx = t * 256 + tid;            // LDS 16B-chunk index
    const int col  = cidx >> 4;
    const int kc   = (cidx & 15) ^ (col & 15); // de-swizzle: fetch this k-chunk
    goff[t] = (unsigned)(col * DIM + kc * 8);
  }

  // ---- swizzled LDS byte offsets for B fragments (job-invariant) ----
  unsigned boff[4][4];
#pragma unroll
  for (int tc = 0; tc < 4; ++tc)
#pragma unroll
    for (int ks = 0; ks < 4; ++ks) {
      const int col = wc * 64 + tc * 16 + c;   // col & 15 == c
      const int kc  = ks * 4 + q;
      boff[tc][ks] = (unsigned)((col * 16 + (kc ^ c)) * 16);
    }

  const f32x4 zero4 = {0.f, 0.f, 0.f, 0.f};
  const short* Gs = (const short*)G;

  for (int sg = 0; sg < 2; ++sg) {
    int rt, cbeg, nct;
    if (sg == 0) {                 // segment in tile-row p
      rt   = p;
      cbeg = p + jb;
      nct  = min(je, split) - jb;
    } else {                       // segment in tile-row 127-p (ct = t-1)
      rt   = 127 - p;
      const int t0 = max(jb, split);
      cbeg = t0 - 1;
      nct  = je - t0;
    }
    if (nct <= 0) continue;

    const int rbw = rt * 128 + wr * 64;

    // ---- A fragments: 64 rows x 128 k per wave, in registers ----
    short8 afrag[4][4];
#pragma unroll
    for (int tr = 0; tr < 4; ++tr)
#pragma unroll
      for (int ks = 0; ks < 4; ++ks) {
        const int row = rbw + tr * 16 + c;
        afrag[tr][ks] = *(const short8*)(Gs + (size_t)row * DIM + ks * 32 + q * 8);
      }

    float rs[4][4];
#pragma unroll
    for (int tr = 0; tr < 4; ++tr)
#pragma unroll
      for (int r = 0; r < 4; ++r) rs[tr][r] = 0.f;

    // ---- prologue: stage first B tile into buffer 0 ----
    {
      const unsigned short* gsrc = G + (size_t)cbeg * 128 * DIM;
#pragma unroll
      for (int t = 0; t < 8; ++t)
        gload_lds16(gsrc + goff[t],
                    (void*)(&Bbuf[0][0] + (size_t)(t * 256 + w * 64) * 8));
    }

    for (int jj = 0; jj < nct; ++jj) {
      const int cur = jj & 1;
      const int ct  = cbeg + jj;
      // drains vmcnt(0): buf[cur] staged (issued one full compute phase ago)
      __syncthreads();

      if (jj + 1 < nct) {  // prefetch next tile into the other buffer
        const unsigned short* gsrc = G + (size_t)(ct + 1) * 128 * DIM;
#pragma unroll
        for (int t = 0; t < 8; ++t)
          gload_lds16(gsrc + goff[t],
                      (void*)(&Bbuf[cur ^ 1][0] + (size_t)(t * 256 + w * 64) * 8));
      }

      const char* bbase = (const char*)&Bbuf[cur][0];
      f32x4 acc[4][4];
#pragma unroll
      for (int ks = 0; ks < 4; ++ks) {
        short8 bfr[4];
#pragma unroll
        for (int tc = 0; tc < 4; ++tc)
          bfr[tc] = *(const short8*)(bbase + boff[tc][ks]);
#pragma unroll
        for (int tr = 0; tr < 4; ++tr)
#pragma unroll
          for (int tc = 0; tc < 4; ++tc) {
            if (ks == 0)
              acc[tr][tc] = __builtin_amdgcn_mfma_f32_16x16x32_bf16(
                  afrag[tr][0], bfr[tc], zero4, 0, 0, 0);
            else
              acc[tr][tc] = __builtin_amdgcn_mfma_f32_16x16x32_bf16(
                  afrag[tr][ks], bfr[tc], acc[tr][tc], 0, 0, 0);
          }
      }

      // diagonal tile: force exp2 arg to 0 -> contributes 1.0 == exp(9e-15/0.07)
      if (ct == rt && wr == wc) {
#pragma unroll
        for (int tr = 0; tr < 4; ++tr)
#pragma unroll
          for (int r = 0; r < 4; ++r)
            if (c == q * 4 + r) acc[tr][tr][r] = 0.f;
      }

      // exp once; feed row sums (regs) and, off-diagonal, col partials
      const bool mirror = (ct != rt);
      float cs[4] = {0.f, 0.f, 0.f, 0.f};
#pragma unroll
      for (int tr = 0; tr < 4; ++tr)
#pragma unroll
        for (int tc = 0; tc < 4; ++tc) {
          const float e0 = __builtin_amdgcn_exp2f(acc[tr][tc][0]);
          const float e1 = __builtin_amdgcn_exp2f(acc[tr][tc][1]);
          const float e2 = __builtin_amdgcn_exp2f(acc[tr][tc][2]);
          const float e3 = __builtin_amdgcn_exp2f(acc[tr][tc][3]);
          rs[tr][0] += e0;
          rs[tr][1] += e1;
          rs[tr][2] += e2;
          rs[tr][3] += e3;
          if (mirror) cs[tc] += (e0 + e1) + (e2 + e3);
        }

      // mirror credit: fire-and-forget atomics (proven cheapest, R1 vs R2/R4)
      if (mirror) {
#pragma unroll
        for (int tc = 0; tc < 4; ++tc) {
          float v = cs[tc];
          v += __shfl_xor(v, 16);
          v += __shfl_xor(v, 32);
          if (q == 0)
            atomicAdd(&rowsum[ct * 128 + wc * 64 + tc * 16 + c], v);
        }
      }
    }

    // ---- segment epilogue: flush row accumulators (16 lanes share a row) ----
#pragma unroll
    for (int tr = 0; tr < 4; ++tr)
#pragma unroll
      for (int r = 0; r < 4; ++r) {
        float v = rs[tr][r];
        v += __shfl_xor(v, 1);
        v += __shfl_xor(v, 2);
        v += __shfl_xor(v, 4);
        v += __shfl_xor(v, 8);
        if (c == 0) atomicAdd(&rowsum[rbw + tr * 16 + q * 4 + r], v);
      }
  }

  // ---- fused finalize: the LAST block computes mean(log(rowsum)) - pos ----
  __shared__ int lastBlk;
  __shared__ float part[4];
  __threadfence();  // release: all this block's rowsum atomics are visible
  if (tid == 0) {
    const unsigned old = atomicAdd(cnt, 1u);
    lastBlk = (old == GRID2 - 1) ? 1 : 0;
  }
  __syncthreads();
  if (!lastBlk) return;
  __threadfence();  // acquire: make all blocks' rowsum contributions visible

  float local = 0.f;
  for (int i = tid; i < N_ROWS; i += 256) local += logf(rowsum[i]);
#pragma unroll
  for (int m = 1; m < 64; m <<= 1) local += __shfl_xor(local, m);
  if ((tid & 63) == 0) part[tid >> 6] = local;
  __syncthreads();
  if (tid == 0 && out) {
    const float ssum = (part[0] + part[1]) + (part[2] + part[3]);
    out[0] = ssum / (float)N_ROWS - POSC;
  }
}

extern "C" void kernel_launch(void* const* d_in, const int* in_sizes, int n_in,
                              void* d_out, int out_size, void* d_ws, size_t ws_size,
                              hipStream_t stream) {
  (void)in_sizes; (void)n_in; (void)out_size; (void)ws_size;
  const float* feats = (const float*)d_in[0];
  // d_in[1] (labels) is arange(N) by construction -> pos_mask == identity.
  unsigned short* G = (unsigned short*)d_ws;                        // 4 MB bf16
  float* rowsum = (float*)((char*)d_ws + (size_t)N_ROWS * DIM * 2); // 64 KB
  unsigned* cnt = (unsigned*)(rowsum + N_ROWS);                     // 4 B

  normalize_kernel<<<dim3(N_ROWS / 4), dim3(256), 0, stream>>>(feats, G, rowsum);
  simclr_lse_kernel<<<dim3(GRID2), dim3(256), 0, stream>>>(
      G, rowsum, cnt, d_out ? (float*)d_out : nullptr);
}

// Round 8
// 120.919 us; speedup vs baseline: 1.5271x; 1.2787x over previous
//
#include <hip/hip_runtime.h>
#include <hip/hip_bf16.h>
#include <stdint.h>

typedef __attribute__((ext_vector_type(8))) short short8;
typedef __attribute__((ext_vector_type(4))) float f32x4;

#define N_ROWS 16384
#define DIM 128

// alpha = 1/sqrt(0.07 * ln2): folds 1/T and the exp->exp2 conversion into the
// normalization, so the MFMA output is directly the exp2 argument.
constexpr float ALPHA = 4.5398160f;
// pos = 9e-15 / 0.07 (the masked diagonal value after temperature scaling)
constexpr float POSC = 1.2857143e-13f;

__device__ __forceinline__ void gload_lds16(const void* g, void* lds) {
  __builtin_amdgcn_global_load_lds(
      (const __attribute__((address_space(1))) void*)(uintptr_t)g,
      (__attribute__((address_space(3))) void*)(uintptr_t)lds,
      16, 0, 0);
}

// ---------------- kernel 1: row-normalize -> bf16, + zero rowsum ----------------
__global__ void normalize_kernel(const float* __restrict__ feats,
                                 unsigned short* __restrict__ G,
                                 float* __restrict__ rowsum) {
  const int tid  = threadIdx.x;
  const int lane = tid & 63;
  const int row  = blockIdx.x * 4 + (tid >> 6);

  const float2 v = *(const float2*)(feats + (size_t)row * DIM + lane * 2);
  float ss = v.x * v.x + v.y * v.y;
#pragma unroll
  for (int m = 1; m < 64; m <<= 1) ss += __shfl_xor(ss, m);
  const float sc = ALPHA / fmaxf(sqrtf(ss), 1e-8f);

  __hip_bfloat16 h0 = __float2bfloat16(v.x * sc);
  __hip_bfloat16 h1 = __float2bfloat16(v.y * sc);
  unsigned int packed = (unsigned int)(*(unsigned short*)&h0) |
                        ((unsigned int)(*(unsigned short*)&h1) << 16);
  *(unsigned int*)(G + (size_t)row * DIM + lane * 2) = packed;

  // zero the 16384-entry rowsum accumulator (ws is poisoned 0xAA each call)
  if (blockIdx.x < 64) rowsum[blockIdx.x * 256 + tid] = 0.f;
}

// ---------------- kernel 2: SYMMETRIC streamed GEMM + sum-of-exp ----------------
// R1 structure (proven 58.3 us): exp(C) symmetric -> only tiles rt <= ct;
// full-tile double-buffered prefetch; mirror col-credits as in-loop
// fire-and-forget atomics (R1 vs R2/R4 A/B: cheapest); row-credits in regs.
// Occupancy is register-quantum-locked at 2 blocks/CU (R3/R6 spills).
//
// R8 changes (schedule-only, no sync changes):
//  - branchless diagonal (was a uniform branch splitting the MFMA/exp block,
//    blocking TRANS/MFMA interleave by the scheduler)
//  - half-tile order: MFMA(h1); MFMA(h2); exp(h1); exp(h2) -> exp(h1) is an
//    independent TRANS stream the scheduler can overlap with h2's MFMA issue
//  - s_setprio(1) around the MFMA cluster (blocks are phase-independent;
//    attn-like case where setprio measured +4-7%)
__global__ __launch_bounds__(256, 2) void simclr_lse_kernel(
    const unsigned short* __restrict__ G, float* __restrict__ rowsum) {
  const int tid  = threadIdx.x;
  const int lane = tid & 63;
  const int w    = tid >> 6;
  const int wr   = w >> 1;   // wave row-half
  const int wc   = w & 1;    // wave col-half
  const int c    = lane & 15;
  const int q    = lane >> 4;

  const int p  = blockIdx.x >> 3;   // pair index 0..63: rows {p, 127-p}
  const int s  = blockIdx.x & 7;    // slice within pair
  const int r8 = p & 7;             // rotate the 17-job slice across pairs
  const int jb = (s * 129 + r8) >> 3;
  const int je = ((s + 1) * 129 + r8) >> 3;
  const int split = 128 - p;        // job t < split -> row tile p, else 127-p

  __shared__ __align__(16) unsigned short Bbuf[2][128 * 128];  // 2 x 32 KB

  // ---- staging gather offsets (job-invariant, in ushort units) ----
  unsigned goff[8];
#pragma unroll
  for (int t = 0; t < 8; ++t) {
    const int cidx = t * 256 + tid;            // LDS 16B-chunk index
    const int col  = cidx >> 4;
    const int kc   = (cidx & 15) ^ (col & 15); // de-swizzle: fetch this k-chunk
    goff[t] = (unsigned)(col * DIM + kc * 8);
  }

  // ---- swizzled LDS byte offsets for B fragments (job-invariant) ----
  unsigned boff[4][4];
#pragma unroll
  for (int tc = 0; tc < 4; ++tc)
#pragma unroll
    for (int ks = 0; ks < 4; ++ks) {
      const int col = wc * 64 + tc * 16 + c;   // col & 15 == c
      const int kc  = ks * 4 + q;
      boff[tc][ks] = (unsigned)((col * 16 + (kc ^ c)) * 16);
    }

  // ---- diagonal lane mask (job-invariant): dsel[r] = (c == q*4+r) ----
  float dsel[4];
#pragma unroll
  for (int r = 0; r < 4; ++r) dsel[r] = (c == q * 4 + r) ? 1.f : 0.f;

  const f32x4 zero4 = {0.f, 0.f, 0.f, 0.f};
  const short* Gs = (const short*)G;

  for (int sg = 0; sg < 2; ++sg) {
    int rt, cbeg, nct;
    if (sg == 0) {                 // segment in tile-row p
      rt   = p;
      cbeg = p + jb;
      nct  = min(je, split) - jb;
    } else {                       // segment in tile-row 127-p (ct = t-1)
      rt   = 127 - p;
      const int t0 = max(jb, split);
      cbeg = t0 - 1;
      nct  = je - t0;
    }
    if (nct <= 0) continue;

    const int rbw = rt * 128 + wr * 64;

    // ---- A fragments: 64 rows x 128 k per wave, in registers ----
    short8 afrag[4][4];
#pragma unroll
    for (int tr = 0; tr < 4; ++tr)
#pragma unroll
      for (int ks = 0; ks < 4; ++ks) {
        const int row = rbw + tr * 16 + c;
        afrag[tr][ks] = *(const short8*)(Gs + (size_t)row * DIM + ks * 32 + q * 8);
      }

    float rs[4][4];
#pragma unroll
    for (int tr = 0; tr < 4; ++tr)
#pragma unroll
      for (int r = 0; r < 4; ++r) rs[tr][r] = 0.f;

    // ---- prologue: stage first B tile into buffer 0 ----
    {
      const unsigned short* gsrc = G + (size_t)cbeg * 128 * DIM;
#pragma unroll
      for (int t = 0; t < 8; ++t)
        gload_lds16(gsrc + goff[t],
                    (void*)(&Bbuf[0][0] + (size_t)(t * 256 + w * 64) * 8));
    }

    for (int jj = 0; jj < nct; ++jj) {
      const int cur = jj & 1;
      const int ct  = cbeg + jj;
      // drains vmcnt(0): buf[cur] staged (issued one full compute phase ago)
      __syncthreads();

      if (jj + 1 < nct) {  // prefetch next tile into the other buffer
        const unsigned short* gsrc = G + (size_t)(ct + 1) * 128 * DIM;
#pragma unroll
        for (int t = 0; t < 8; ++t)
          gload_lds16(gsrc + goff[t],
                      (void*)(&Bbuf[cur ^ 1][0] + (size_t)(t * 256 + w * 64) * 8));
      }

      const char* bbase = (const char*)&Bbuf[cur][0];

      __builtin_amdgcn_s_setprio(1);
      // ---- half 1 MFMAs: tc = 0,1 ----
      f32x4 acc1[4][2];
#pragma unroll
      for (int ks = 0; ks < 4; ++ks) {
        const short8 b0 = *(const short8*)(bbase + boff[0][ks]);
        const short8 b1 = *(const short8*)(bbase + boff[1][ks]);
#pragma unroll
        for (int tr = 0; tr < 4; ++tr) {
          if (ks == 0) {
            acc1[tr][0] = __builtin_amdgcn_mfma_f32_16x16x32_bf16(
                afrag[tr][0], b0, zero4, 0, 0, 0);
            acc1[tr][1] = __builtin_amdgcn_mfma_f32_16x16x32_bf16(
                afrag[tr][0], b1, zero4, 0, 0, 0);
          } else {
            acc1[tr][0] = __builtin_amdgcn_mfma_f32_16x16x32_bf16(
                afrag[tr][ks], b0, acc1[tr][0], 0, 0, 0);
            acc1[tr][1] = __builtin_amdgcn_mfma_f32_16x16x32_bf16(
                afrag[tr][ks], b1, acc1[tr][1], 0, 0, 0);
          }
        }
      }
      // ---- half 2 MFMAs: tc = 2,3 (exp(h1) below can interleave here) ----
      f32x4 acc2[4][2];
#pragma unroll
      for (int ks = 0; ks < 4; ++ks) {
        const short8 b2 = *(const short8*)(bbase + boff[2][ks]);
        const short8 b3 = *(const short8*)(bbase + boff[3][ks]);
#pragma unroll
        for (int tr = 0; tr < 4; ++tr) {
          if (ks == 0) {
            acc2[tr][0] = __builtin_amdgcn_mfma_f32_16x16x32_bf16(
                afrag[tr][0], b2, zero4, 0, 0, 0);
            acc2[tr][1] = __builtin_amdgcn_mfma_f32_16x16x32_bf16(
                afrag[tr][0], b3, zero4, 0, 0, 0);
          } else {
            acc2[tr][0] = __builtin_amdgcn_mfma_f32_16x16x32_bf16(
                afrag[tr][ks], b2, acc2[tr][0], 0, 0, 0);
            acc2[tr][1] = __builtin_amdgcn_mfma_f32_16x16x32_bf16(
                afrag[tr][ks], b3, acc2[tr][1], 0, 0, 0);
          }
        }
      }
      __builtin_amdgcn_s_setprio(0);

      // ---- branchless diagonal select + exp + accumulate ----
      // sel[r] = 1 on true-diagonal elements of THIS job, else 0;
      // e' = e + sel*(1-e)  (exp(9e-15/0.07) == 1.0)
      const float dj = (ct == rt && wr == wc) ? 1.f : 0.f;
      float sel[4];
#pragma unroll
      for (int r = 0; r < 4; ++r) sel[r] = dj * dsel[r];

      const bool mirror = (ct != rt);
      float cs[4] = {0.f, 0.f, 0.f, 0.f};
      // half 1: tiles (tr, tc=0,1); diag tiles here are (0,0),(1,1)
#pragma unroll
      for (int tr = 0; tr < 4; ++tr)
#pragma unroll
        for (int tc = 0; tc < 2; ++tc)
#pragma unroll
          for (int r = 0; r < 4; ++r) {
            float e = __builtin_amdgcn_exp2f(acc1[tr][tc][r]);
            if (tr == tc) e = fmaf(sel[r], 1.f - e, e);
            rs[tr][r] += e;
            cs[tc] += e;
          }
      // half 2: tiles (tr, tc=2,3); diag tiles here are (2,2),(3,3)
#pragma unroll
      for (int tr = 0; tr < 4; ++tr)
#pragma unroll
        for (int tc2 = 0; tc2 < 2; ++tc2) {
          const int tc = tc2 + 2;
#pragma unroll
          for (int r = 0; r < 4; ++r) {
            float e = __builtin_amdgcn_exp2f(acc2[tr][tc2][r]);
            if (tr == tc) e = fmaf(sel[r], 1.f - e, e);
            rs[tr][r] += e;
            cs[tc] += e;
          }
        }

      // mirror credit: fire-and-forget atomics (proven cheapest, R1 vs R2/R4)
      if (mirror) {
#pragma unroll
        for (int tc = 0; tc < 4; ++tc) {
          float v = cs[tc];
          v += __shfl_xor(v, 16);
          v += __shfl_xor(v, 32);
          if (q == 0)
            atomicAdd(&rowsum[ct * 128 + wc * 64 + tc * 16 + c], v);
        }
      }
    }

    // ---- segment epilogue: flush row accumulators (16 lanes share a row) ----
#pragma unroll
    for (int tr = 0; tr < 4; ++tr)
#pragma unroll
      for (int r = 0; r < 4; ++r) {
        float v = rs[tr][r];
        v += __shfl_xor(v, 1);
        v += __shfl_xor(v, 2);
        v += __shfl_xor(v, 4);
        v += __shfl_xor(v, 8);
        if (c == 0) atomicAdd(&rowsum[rbw + tr * 16 + q * 4 + r], v);
      }
  }
}

// ---------------- kernel 3: mean of log(rowsum) - pos ----------------
__global__ void finalize_kernel(const float* __restrict__ rowsum,
                                float* __restrict__ out) {
  const int tid = threadIdx.x;
  float local = 0.f;
  for (int i = tid; i < N_ROWS; i += 1024) local += logf(rowsum[i]);
#pragma unroll
  for (int m = 1; m < 64; m <<= 1) local += __shfl_xor(local, m);
  __shared__ float part[16];
  if ((tid & 63) == 0) part[tid >> 6] = local;
  __syncthreads();
  if (tid == 0) {
    float s = 0.f;
#pragma unroll
    for (int i = 0; i < 16; ++i) s += part[i];
    out[0] = s / (float)N_ROWS - POSC;
  }
}

extern "C" void kernel_launch(void* const* d_in, const int* in_sizes, int n_in,
                              void* d_out, int out_size, void* d_ws, size_t ws_size,
                              hipStream_t stream) {
  (void)in_sizes; (void)n_in; (void)out_size; (void)ws_size;
  const float* feats = (const float*)d_in[0];
  // d_in[1] (labels) is arange(N) by construction -> pos_mask == identity.
  unsigned short* G = (unsigned short*)d_ws;                        // 4 MB bf16
  float* rowsum = (float*)((char*)d_ws + (size_t)N_ROWS * DIM * 2); // 64 KB

  normalize_kernel<<<dim3(N_ROWS / 4), dim3(256), 0, stream>>>(feats, G, rowsum);
  simclr_lse_kernel<<<dim3(512), dim3(256), 0, stream>>>(G, rowsum);
  finalize_kernel<<<dim3(1), dim3(1024), 0, stream>>>(rowsum, d_out ? (float*)d_out : nullptr);
}

// Round 9
// 116.866 us; speedup vs baseline: 1.5801x; 1.0347x over previous
//
#include <hip/hip_runtime.h>
#include <hip/hip_bf16.h>
#include <stdint.h>

typedef __attribute__((ext_vector_type(8))) short short8;
typedef __attribute__((ext_vector_type(4))) float f32x4;

#define N_ROWS 16384
#define DIM 128

// alpha = 1/sqrt(0.07 * ln2): folds 1/T and the exp->exp2 conversion into the
// normalization, so the MFMA output is directly the exp2 argument.
constexpr float ALPHA = 4.5398160f;
// pos = 9e-15 / 0.07 (the masked diagonal value after temperature scaling)
constexpr float POSC = 1.2857143e-13f;

__device__ __forceinline__ void gload_lds16(const void* g, void* lds) {
  __builtin_amdgcn_global_load_lds(
      (const __attribute__((address_space(1))) void*)(uintptr_t)g,
      (__attribute__((address_space(3))) void*)(uintptr_t)lds,
      16, 0, 0);
}

// ---------------- kernel 1: row-normalize -> bf16, + zero rowsum ----------------
__global__ void normalize_kernel(const float* __restrict__ feats,
                                 unsigned short* __restrict__ G,
                                 float* __restrict__ rowsum) {
  const int tid  = threadIdx.x;
  const int lane = tid & 63;
  const int row  = blockIdx.x * 4 + (tid >> 6);

  const float2 v = *(const float2*)(feats + (size_t)row * DIM + lane * 2);
  float ss = v.x * v.x + v.y * v.y;
#pragma unroll
  for (int m = 1; m < 64; m <<= 1) ss += __shfl_xor(ss, m);
  const float sc = ALPHA / fmaxf(sqrtf(ss), 1e-8f);

  __hip_bfloat16 h0 = __float2bfloat16(v.x * sc);
  __hip_bfloat16 h1 = __float2bfloat16(v.y * sc);
  unsigned int packed = (unsigned int)(*(unsigned short*)&h0) |
                        ((unsigned int)(*(unsigned short*)&h1) << 16);
  *(unsigned int*)(G + (size_t)row * DIM + lane * 2) = packed;

  // zero the 16384-entry rowsum accumulator (ws is poisoned 0xAA each call)
  if (blockIdx.x < 64) rowsum[blockIdx.x * 256 + tid] = 0.f;
}

// ---------------- kernel 2: SYMMETRIC streamed GEMM + sum-of-exp --------------
// R1 mechanics (proven best): exp(C) symmetric -> only tiles rt <= ct;
// full-tile double-buffered prefetch; mirror col-credits as in-loop
// fire-and-forget atomics; row-credits in regs, flushed per segment.
//
// R9 change: 512-thread blocks (8 waves, wave = 32 rows x 64 cols) to SHRINK
// per-wave register state below the 128-reg occupancy quantum:
//   afrag[2][4]=32 + acc[2][4]=32 + rs 8 + cs 4 + boff 4 + goff 4 + misc
//   ~ 110 regs  ->  4 waves/SIMD (16 waves/CU), double the TLP of R0-R8.
// R8 proved intra-wave scheduling is null; the 46% idle issue slots need
// more waves, and this layout is the spill-free way to get them (R3/R6
// showed capping without shrinking state = scratch disaster).
// Decomposition: pair tile-row p with 127-p -> 129 jobs, 8 balanced slices,
// 64 pairs -> 512 blocks = exactly 2 blocks/CU. LDS 64KB x 2 = 128 <= 160.
__global__ __launch_bounds__(512, 4) void simclr_lse_kernel(
    const unsigned short* __restrict__ G, float* __restrict__ rowsum) {
  const int tid  = threadIdx.x;          // 0..511
  const int lane = tid & 63;
  const int w    = tid >> 6;             // 0..7
  const int wrow = w >> 1;               // 0..3 : 32-row band
  const int wcol = w & 1;                // 0..1 : 64-col half
  const int c    = lane & 15;
  const int q    = lane >> 4;

  const int p  = blockIdx.x >> 3;   // pair index 0..63: rows {p, 127-p}
  const int s  = blockIdx.x & 7;    // slice within pair
  const int r8 = p & 7;             // rotate the 17-job slice across pairs
  const int jb = (s * 129 + r8) >> 3;
  const int je = ((s + 1) * 129 + r8) >> 3;
  const int split = 128 - p;        // job t < split -> row tile p, else 127-p

  __shared__ __align__(16) unsigned short Bbuf[2][128 * 128];  // 2 x 32 KB

  // ---- staging gather offsets (job-invariant, in ushort units) ----
  // 512 threads x 16 B = 8 KB/round; 4 rounds per 32 KB tile.
  unsigned goff[4];
#pragma unroll
  for (int t = 0; t < 4; ++t) {
    const int cidx = t * 512 + tid;            // LDS 16B-chunk index
    const int col  = cidx >> 4;
    const int kc   = (cidx & 15) ^ (col & 15); // de-swizzle: fetch this k-chunk
    goff[t] = (unsigned)(col * DIM + kc * 8);
  }

  // ---- swizzled LDS byte offsets for B fragments: tc folds into the
  //      ds_read immediate (+4096*tc), only the ks dimension needs regs ----
  unsigned boff[4];
#pragma unroll
  for (int ks = 0; ks < 4; ++ks) {
    const int col0 = wcol * 64 + c;            // tc=0 column; col0 & 15 == c
    const int kc   = ks * 4 + q;
    boff[ks] = (unsigned)((col0 * 16 + (kc ^ c)) * 16);
  }

  const f32x4 zero4 = {0.f, 0.f, 0.f, 0.f};
  const short* Gs = (const short*)G;

  for (int sg = 0; sg < 2; ++sg) {
    int rt, cbeg, nct;
    if (sg == 0) {                 // segment in tile-row p
      rt   = p;
      cbeg = p + jb;
      nct  = min(je, split) - jb;
    } else {                       // segment in tile-row 127-p (ct = t-1)
      rt   = 127 - p;
      const int t0 = max(jb, split);
      cbeg = t0 - 1;
      nct  = je - t0;
    }
    if (nct <= 0) continue;

    const int rbw = rt * 128 + wrow * 32;

    // ---- A fragments: 32 rows x 128 k per wave, in registers ----
    short8 afrag[2][4];
#pragma unroll
    for (int tr = 0; tr < 2; ++tr)
#pragma unroll
      for (int ks = 0; ks < 4; ++ks) {
        const int row = rbw + tr * 16 + c;
        afrag[tr][ks] = *(const short8*)(Gs + (size_t)row * DIM + ks * 32 + q * 8);
      }

    float rs[2][4];
#pragma unroll
    for (int tr = 0; tr < 2; ++tr)
#pragma unroll
      for (int r = 0; r < 4; ++r) rs[tr][r] = 0.f;

    // ---- prologue: stage first B tile into buffer 0 ----
    {
      const unsigned short* gsrc = G + (size_t)cbeg * 128 * DIM;
#pragma unroll
      for (int t = 0; t < 4; ++t)
        gload_lds16(gsrc + goff[t],
                    (void*)(&Bbuf[0][0] + (size_t)(t * 512 + w * 64) * 8));
    }

    for (int jj = 0; jj < nct; ++jj) {
      const int cur = jj & 1;
      const int ct  = cbeg + jj;
      // drains vmcnt(0): buf[cur] staged (issued one full compute phase ago)
      __syncthreads();

      if (jj + 1 < nct) {  // prefetch next tile into the other buffer
        const unsigned short* gsrc = G + (size_t)(ct + 1) * 128 * DIM;
#pragma unroll
        for (int t = 0; t < 4; ++t)
          gload_lds16(gsrc + goff[t],
                      (void*)(&Bbuf[cur ^ 1][0] + (size_t)(t * 512 + w * 64) * 8));
      }

      const char* bbase = (const char*)&Bbuf[cur][0];
      f32x4 acc[2][4];
#pragma unroll
      for (int ks = 0; ks < 4; ++ks) {
        short8 bfr[4];
#pragma unroll
        for (int tc = 0; tc < 4; ++tc)
          bfr[tc] = *(const short8*)(bbase + boff[ks] + tc * 4096);
#pragma unroll
        for (int tr = 0; tr < 2; ++tr)
#pragma unroll
          for (int tc = 0; tc < 4; ++tc) {
            if (ks == 0)
              acc[tr][tc] = __builtin_amdgcn_mfma_f32_16x16x32_bf16(
                  afrag[tr][0], bfr[tc], zero4, 0, 0, 0);
            else
              acc[tr][tc] = __builtin_amdgcn_mfma_f32_16x16x32_bf16(
                  afrag[tr][ks], bfr[tc], acc[tr][tc], 0, 0, 0);
          }
      }

      // diagonal tile: the 2 diag fragments of this wave are (tr, t0+tr) with
      // t0 = (wrow&1)*2, and only waves with (wrow>>1)==wcol hold any.
      // Force exp2 arg to 0 -> contributes 1.0 == exp(9e-15/0.07).
      if (ct == rt && (wrow >> 1) == wcol) {
        if ((wrow & 1) == 0) {
#pragma unroll
          for (int r = 0; r < 4; ++r)
            if (c == q * 4 + r) { acc[0][0][r] = 0.f; acc[1][1][r] = 0.f; }
        } else {
#pragma unroll
          for (int r = 0; r < 4; ++r)
            if (c == q * 4 + r) { acc[0][2][r] = 0.f; acc[1][3][r] = 0.f; }
        }
      }

      // exp once; feed row sums (regs) and, off-diagonal, col partials
      const bool mirror = (ct != rt);
      float cs[4] = {0.f, 0.f, 0.f, 0.f};
#pragma unroll
      for (int tr = 0; tr < 2; ++tr)
#pragma unroll
        for (int tc = 0; tc < 4; ++tc) {
          const float e0 = __builtin_amdgcn_exp2f(acc[tr][tc][0]);
          const float e1 = __builtin_amdgcn_exp2f(acc[tr][tc][1]);
          const float e2 = __builtin_amdgcn_exp2f(acc[tr][tc][2]);
          const float e3 = __builtin_amdgcn_exp2f(acc[tr][tc][3]);
          rs[tr][0] += e0;
          rs[tr][1] += e1;
          rs[tr][2] += e2;
          rs[tr][3] += e3;
          if (mirror) cs[tc] += (e0 + e1) + (e2 + e3);
        }

      // mirror credit: fire-and-forget atomics (proven cheapest, R1 vs R2/R4)
      if (mirror) {
#pragma unroll
        for (int tc = 0; tc < 4; ++tc) {
          float v = cs[tc];
          v += __shfl_xor(v, 16);
          v += __shfl_xor(v, 32);
          if (q == 0)
            atomicAdd(&rowsum[ct * 128 + wcol * 64 + tc * 16 + c], v);
        }
      }
    }

    // ---- segment epilogue: flush row accumulators (16 lanes share a row) ----
#pragma unroll
    for (int tr = 0; tr < 2; ++tr)
#pragma unroll
      for (int r = 0; r < 4; ++r) {
        float v = rs[tr][r];
        v += __shfl_xor(v, 1);
        v += __shfl_xor(v, 2);
        v += __shfl_xor(v, 4);
        v += __shfl_xor(v, 8);
        if (c == 0) atomicAdd(&rowsum[rbw + tr * 16 + q * 4 + r], v);
      }
  }
}

// ---------------- kernel 3: mean of log(rowsum) - pos ----------------
__global__ void finalize_kernel(const float* __restrict__ rowsum,
                                float* __restrict__ out) {
  const int tid = threadIdx.x;
  float local = 0.f;
  for (int i = tid; i < N_ROWS; i += 1024) local += logf(rowsum[i]);
#pragma unroll
  for (int m = 1; m < 64; m <<= 1) local += __shfl_xor(local, m);
  __shared__ float part[16];
  if ((tid & 63) == 0) part[tid >> 6] = local;
  __syncthreads();
  if (tid == 0) {
    float s = 0.f;
#pragma unroll
    for (int i = 0; i < 16; ++i) s += part[i];
    out[0] = s / (float)N_ROWS - POSC;
  }
}

extern "C" void kernel_launch(void* const* d_in, const int* in_sizes, int n_in,
                              void* d_out, int out_size, void* d_ws, size_t ws_size,
                              hipStream_t stream) {
  (void)in_sizes; (void)n_in; (void)out_size; (void)ws_size;
  const float* feats = (const float*)d_in[0];
  // d_in[1] (labels) is arange(N) by construction -> pos_mask == identity.
  unsigned short* G = (unsigned short*)d_ws;                        // 4 MB bf16
  float* rowsum = (float*)((char*)d_ws + (size_t)N_ROWS * DIM * 2); // 64 KB

  normalize_kernel<<<dim3(N_ROWS / 4), dim3(256), 0, stream>>>(feats, G, rowsum);
  // 512 blocks x 512 threads: 2 blocks/CU, 16 waves/CU (4/SIMD)
  simclr_lse_kernel<<<dim3(512), dim3(512), 0, stream>>>(G, rowsum);
  finalize_kernel<<<dim3(1), dim3(1024), 0, stream>>>(rowsum, d_out ? (float*)d_out : nullptr);
}